// Round 12
// baseline (196.750 us; speedup 1.0000x reference)
//
#include <hip/hip_runtime.h>
#include <math.h>

// ---------------------------------------------------------------------------
// u-space aggregation + fused Z-build + MFMA epilogue.
//   Z_t(Y_e) built in LDS per 512-edge chunk (dst-sorted range is contiguous
//   per block); gather accumulates G in registers; MFMA vs folded WBT.
// Workspace (4B words):
//   cg      [0..128)        CG tensors (alpha/norm folded)
//   cursor  [128 .. +N)     memset0 -> hist -> prefix -> cursor -> row ends
//   eorder  [.. +E)         edge ids sorted by dst
//   fb      [.. +64N)       feat bf16 [N][32] uint2 {P(s,vx),P(vy,vz)}
//   WBT     [.. +22528)     ushort [128][352]  (W bf16, cg0/c2 folded)
//   tilesums[.. +256)       per-tile sums for hierarchical scan
// ---------------------------------------------------------------------------

typedef __attribute__((ext_vector_type(8))) short bf16x8;
typedef __attribute__((ext_vector_type(4))) float f32x4;

__device__ inline float blo(unsigned u) { return __uint_as_float(u << 16); }
__device__ inline float bhi(unsigned u) { return __uint_as_float(u & 0xffff0000u); }
__device__ inline unsigned bpack(float a, float b) {
    unsigned ua = __float_as_uint(a);
    ua = (ua + 0x7fffu + ((ua >> 16) & 1u)) >> 16;
    unsigned ub = __float_as_uint(b);
    ub = (ub + 0x7fffu + ((ub >> 16) & 1u)) & 0xffff0000u;
    return ua | ub;
}
__device__ inline unsigned short bh(float a) {
    unsigned ua = __float_as_uint(a);
    return (unsigned short)((ua + 0x7fffu + ((ua >> 16) & 1u)) >> 16);
}

// f32 factorial (all n <= 7 here; exact in f32). Register-only scalar loop.
__device__ inline float dfactf(int n) {
    float r = 1.0f;
    for (int i = 2; i <= n; ++i) r *= (float)i;
    return r;
}

// SU(2) "CG" element via the reference's exact Racah-form (all six m-dependent
// factorials in the NUMERATOR — non-standard but matches the reference).
__device__ float su2_cg_elem_f(int l1, int l2, int l3, int i, int k, int n) {
    int m1 = i - l1, m2 = k - l2, m3 = n - l3;
    if (m1 + m2 != m3) return 0.0f;
    int vmin = -l1 + l2 + m3;
    if (-l1 + m1 > vmin) vmin = -l1 + m1;
    if (0 > vmin) vmin = 0;
    int vmax = l2 + l3 + m1;
    if (l3 - l1 + l2 < vmax) vmax = l3 - l1 + l2;
    if (l3 + m3 < vmax) vmax = l3 + m3;
    if (vmax < vmin) return 0.0f;
    float c = sqrtf((float)(2 * l3 + 1) * dfactf(l3 + l1 - l2) *
                    dfactf(l3 - l1 + l2) * dfactf(l1 + l2 - l3) /
                    dfactf(l1 + l2 + l3 + 1));
    c *= sqrtf(dfactf(l3 + m3) * dfactf(l3 - m3) * dfactf(l1 - m1) *
               dfactf(l1 + m1) * dfactf(l2 - m2) * dfactf(l2 + m2));
    float s = 0.0f;
    for (int v = vmin; v <= vmax; ++v) {
        float term = dfactf(l2 + l3 + m1 - v) * dfactf(l1 - m1 + v) /
                     (dfactf(v) * dfactf(l3 - l1 + l2 - v) *
                      dfactf(l3 + m3 - v) * dfactf(v + l1 - l2 - m3));
        if ((v + l2 + m2) & 1) term = -term;
        s += term;
    }
    return c * s;
}

// cg compute by one 256-thread block. All dynamically-indexed arrays in LDS
// (runtime-indexed private arrays go to SCRATCH -> 110us straggler, rule #20).
__device__ void cg_compute_block(float* __restrict__ cg_out) {
    __shared__ float sqr[3][5][5], sqi[3][5][5];  // q matrices for l=0,1,2
    __shared__ float vals[5][45];
    int t = threadIdx.x;
    if (t < 75) {
        int l = t / 25, a = (t % 25) / 5, b = t % 5;
        float re = 0.f, im = 0.f;
        const float inv = 0.70710678118654752440f;
        int m = a - l;
        if (a < 5 && b < 5) {
            if (m < 0) {
                if (b == l - m) re = inv;        // col l+|m|
                if (b == l + m) im = -inv;       // col l-|m|
            } else if (m == 0) {
                if (b == l && a == l) re = 1.f;
            } else {
                float sgn = (m & 1) ? -1.f : 1.f;
                if (b == l + m) re = sgn * inv;
                if (b == l - m) im = sgn * inv;
            }
        }
        if (l == 1) { float r = re; re = im; im = -r; }      // * (-i)
        else if (l == 2) { re = -re; im = -im; }             // * (-1)
        sqr[l][a][b] = re;
        sqi[l][a][b] = im;
    }
    __syncthreads();
    const int l1s[5] = {0, 0, 1, 1, 1};
    const int l2s[5] = {0, 1, 0, 1, 2};
    const int l3s[5] = {0, 1, 1, 0, 1};
    const int offs[5] = {0, 1, 10, 19, 28};
    const float alphas[5] = {0.125f, 0.10206207261596575f, 0.10206207261596575f,
                             0.125f, 0.10206207261596575f};
    int p = t / 45, idx = t % 45;
    bool active = (t < 225);
    float acc = 0.0f;
    int d1 = 0, d2 = 0, d3 = 0;
    if (active) {
        int l1 = l1s[p], l2 = l2s[p], l3 = l3s[p];
        d1 = 2 * l1 + 1; d2 = 2 * l2 + 1; d3 = 2 * l3 + 1;
        if (idx < d1 * d2 * d3) {
            int j = idx / (d2 * d3);
            int rem = idx % (d2 * d3);
            int l_ = rem / d3, m = rem % d3;
            for (int i = 0; i < d1; ++i)
                for (int k = 0; k < d2; ++k)
                    for (int n = 0; n < d3; ++n) {
                        float C = su2_cg_elem_f(l1, l2, l3, i, k, n);
                        if (C == 0.0f) continue;
                        float ar = sqr[l1][i][j], ai = sqi[l1][i][j];
                        float br = sqr[l2][k][l_], bi = sqi[l2][k][l_];
                        float cr = sqr[l3][n][m], ci = sqi[l3][n][m];
                        float abr = ar * br - ai * bi;
                        float abi = ar * bi + ai * br;
                        acc += (abr * cr + abi * ci) * C;  // Re(a*b*conj(c))
                    }
        }
        vals[p][idx] = acc;
    }
    __syncthreads();
    if (active && idx < d1 * d2 * d3) {
        float n2 = 0.0f;
        for (int q = 0; q < 45; ++q) n2 += vals[p][q] * vals[p][q];
        cg_out[offs[p] + idx] = acc * alphas[p] / sqrtf(n2);
    }
}

// ---------------------------------------------------------------------------
// prep: cg (block 0, LDS-based) + feat->bf16 transcode + dst histogram
// ---------------------------------------------------------------------------
__global__ __launch_bounds__(256) void prep_kernel(
    const float* __restrict__ feat, const int* __restrict__ eidx,
    int* __restrict__ cursor, unsigned* __restrict__ fb,
    float* __restrict__ cg, int N, int E) {
    if (blockIdx.x == 0) cg_compute_block(cg);
    int t = blockIdx.x * 256 + threadIdx.x;
    if (t < N * 32) {
        int n = t >> 5, u = t & 31;
        const float* f = feat + (size_t)n * 128;
        float s = f[u];
        float vx = f[32 + 3 * u], vy = f[33 + 3 * u], vz = f[34 + 3 * u];
        ((uint2*)fb)[t] = make_uint2(bpack(s, vx), bpack(vy, vz));
    }
    if (t < E) atomicAdd(&cursor[eidx[E + t]], 1);
}

// ---------------------------------------------------------------------------
// scanA (fused with WBT build)
// WBT[j][k], k = t*32+u:  j<32 (out0): t0 -> cg0*w0, t1 -> w3
//   j>=32: w=(j-32)/3, m=(j-32)%3: t2+mm -> (mm==m)*w1 ;
//   t5+i -> c2[i][m]*w2 ; t8+mm -> (mm==m)*w4
// ---------------------------------------------------------------------------
__global__ __launch_bounds__(256) void scanA_kernel(
    const int* __restrict__ counts, int* __restrict__ tilesums, int N,
    const float* __restrict__ W, const float* __restrict__ cg,
    unsigned short* __restrict__ WBT) {
    __shared__ int lds[4];
    int i = blockIdx.x * 256 + threadIdx.x;
    int v = (i < N) ? counts[i] : 0;
#pragma unroll
    for (int d = 1; d < 64; d <<= 1) v += __shfl_xor(v, d);
    int wid = threadIdx.x >> 6;
    if ((threadIdx.x & 63) == 0) lds[wid] = v;
    __syncthreads();
    if (threadIdx.x == 0)
        tilesums[blockIdx.x] = lds[0] + lds[1] + lds[2] + lds[3];
    int idx = i;
    if (idx < 128 * 352) {
        int j = idx / 352, k = idx % 352;
        int t = k >> 5, u = k & 31;
        float val = 0.f;
        if (j < 32) {
            if (t == 0) val = cg[0] * W[u * 32 + j];
            else if (t == 1) val = W[3072 + u * 32 + j];
        } else {
            int w = (j - 32) / 3, m = (j - 32) % 3;
            if (t >= 2 && t <= 4) { if (t - 2 == m) val = W[1024 + u * 32 + w]; }
            else if (t >= 5 && t <= 7) { val = cg[10 + (t - 5) * 3 + m] * W[2048 + u * 32 + w]; }
            else if (t >= 8) { if (t - 8 == m) val = W[4096 + u * 32 + w]; }
        }
        WBT[idx] = bh(val);
    }
}

__global__ __launch_bounds__(256) void scanB_kernel(
    int* __restrict__ tilesums, int tiles) {
    __shared__ int lds[4];
    int tid = threadIdx.x;
    int v = (tid < tiles) ? tilesums[tid] : 0;
    int orig = v;
#pragma unroll
    for (int d = 1; d < 64; d <<= 1) {
        int t = __shfl_up(v, d);
        if ((tid & 63) >= d) v += t;
    }
    int wid = tid >> 6;
    if ((tid & 63) == 63) lds[wid] = v;
    __syncthreads();
    int base = 0;
    for (int q = 0; q < wid; ++q) base += lds[q];
    if (tid < tiles) tilesums[tid] = base + v - orig;  // exclusive
}

__global__ __launch_bounds__(256) void scanC_kernel(
    int* __restrict__ counts, const int* __restrict__ tilesums, int N) {
    __shared__ int lds[4];
    int i = blockIdx.x * 256 + threadIdx.x;
    int tid = threadIdx.x;
    int v = (i < N) ? counts[i] : 0;
    int orig = v;
#pragma unroll
    for (int d = 1; d < 64; d <<= 1) {
        int t = __shfl_up(v, d);
        if ((tid & 63) >= d) v += t;
    }
    int wid = tid >> 6;
    if ((tid & 63) == 63) lds[wid] = v;
    __syncthreads();
    int base = tilesums[blockIdx.x];
    for (int q = 0; q < wid; ++q) base += lds[q];
    if (i < N) counts[i] = base + v - orig;  // exclusive prefix
}

// ---------------------------------------------------------------------------
// scatter_ids: 4B id sort by dst (light scattered writes only)
// ---------------------------------------------------------------------------
__global__ __launch_bounds__(256) void scatter_ids_kernel(
    const int* __restrict__ eidx, int* __restrict__ cursor,
    int* __restrict__ eorder, int E) {
    int t = blockIdx.x * 256 + threadIdx.x;
    if (t >= E) return;
    int pos = atomicAdd(&cursor[eidx[E + t]], 1);
    eorder[pos] = t;
}
// After scatter_ids: cursor[d] == end of d's range.

// ---------------------------------------------------------------------------
// Fused Z-build + gather + MFMA. 512 threads (8 waves) per 16-dst tile.
// The block's dst-sorted edge positions form ONE contiguous range [r0,r1).
// Per 512-edge chunk: each thread builds Z for one sorted edge into LDS
// (random sh reads, no Z intermediate in global), barrier; each wave gathers
// its 2 dsts' edges from the chunk (LDS broadcast + random fb), accumulators
// persist across chunks. Epilogue: shfl combine, Gs in LDS, 8 waves x 1
// j-tile of mfma_f32_16x16x32_bf16 vs WBT.
// Zs row layout (12 uints): [0]=src, [2]=P(Y0,Z1_0), [3]=P(Z1_1,Z1_2),
//  [4]=P(Z3_0,Z3_1), [5]=P(Z3_2,Z4_00), [6]=P(Z4_01,Z4_02),
//  [7]=P(Z4_10,Z4_11), [8]=P(Z4_12,Z4_20), [9]=P(Z4_21,Z4_22)
// ---------------------------------------------------------------------------
__global__ __launch_bounds__(512) void gather_mfma_kernel(
    const unsigned* __restrict__ fb, const float* __restrict__ sh,
    const int* __restrict__ eidx, const int* __restrict__ eorder,
    const int* __restrict__ cursor, const unsigned short* __restrict__ WBT,
    const float* __restrict__ cg, float* __restrict__ out, int N) {
    __shared__ unsigned Zs[512][12];
    __shared__ unsigned short Gs[16][360];
    int tid = threadIdx.x;
    int wv = tid >> 6, lane = tid & 63;
    int half = lane >> 5, u = lane & 31;
    int base = blockIdx.x << 4;
    int lastnode = (base + 15 < N) ? base + 15 : N - 1;
    int r0 = base ? cursor[base - 1] : 0;
    int r1 = cursor[lastnode];

    int s0 = 0, e0 = 0, s1 = 0, e1 = 0;
    {
        int na = base + wv * 2, nb = na + 1;
        if (na < N) { s0 = na ? cursor[na - 1] : 0; e0 = cursor[na]; }
        if (nb < N) { s1 = cursor[nb - 1]; e1 = cursor[nb]; }
    }
    float g[2][11];
#pragma unroll
    for (int d = 0; d < 2; ++d)
#pragma unroll
        for (int k = 0; k < 11; ++k) g[d][k] = 0.f;

    for (int c0 = r0; c0 < r1; c0 += 512) {
        int c1 = (c0 + 512 < r1) ? c0 + 512 : r1;
        __syncthreads();  // protect Zs reuse across chunks
        if (tid < c1 - c0) {
            int e = eorder[c0 + tid];
            int src = eidx[e];
            const float* Ye = sh + (size_t)e * 9;
            float Y0 = Ye[0];
            float Y1v[3] = {Ye[1], Ye[2], Ye[3]};
            float Y2v[5] = {Ye[4], Ye[5], Ye[6], Ye[7], Ye[8]};
            float Z1[3], Z3[3], Z4[9];
#pragma unroll
            for (int m = 0; m < 3; ++m)
                Z1[m] = fmaf(Y1v[0], cg[1 + m],
                        fmaf(Y1v[1], cg[4 + m], Y1v[2] * cg[7 + m]));
#pragma unroll
            for (int i = 0; i < 3; ++i)
                Z3[i] = fmaf(Y1v[0], cg[19 + i * 3],
                        fmaf(Y1v[1], cg[19 + i * 3 + 1], Y1v[2] * cg[19 + i * 3 + 2]));
#pragma unroll
            for (int i = 0; i < 3; ++i)
#pragma unroll
                for (int m = 0; m < 3; ++m) {
                    float acc = 0.f;
#pragma unroll
                    for (int j = 0; j < 5; ++j)
                        acc = fmaf(Y2v[j], cg[28 + (i * 5 + j) * 3 + m], acc);
                    Z4[i * 3 + m] = acc;
                }
            unsigned* Zr = Zs[tid];
            Zr[0] = (unsigned)src;
            Zr[2] = bpack(Y0, Z1[0]);
            Zr[3] = bpack(Z1[1], Z1[2]);
            Zr[4] = bpack(Z3[0], Z3[1]);
            Zr[5] = bpack(Z3[2], Z4[0]);
            Zr[6] = bpack(Z4[1], Z4[2]);
            Zr[7] = bpack(Z4[3], Z4[4]);
            Zr[8] = bpack(Z4[5], Z4[6]);
            Zr[9] = bpack(Z4[7], Z4[8]);
        }
        __syncthreads();
#pragma unroll
        for (int d = 0; d < 2; ++d) {
            int s = d ? s1 : s0;
            int e = d ? e1 : e0;
            int lo = (s > c0) ? s : c0;
            int hi = (e < c1) ? e : c1;
            int first = lo + ((s + half - lo) & 1);  // keep (idx-s)&1 == half
            for (int idx = first; idx < hi; idx += 2) {
                const unsigned* Zr = Zs[idx - c0];
                int src = (int)Zr[0];
                uint2 z0 = *(const uint2*)(Zr + 2);
                uint2 z1 = *(const uint2*)(Zr + 4);
                uint2 z2 = *(const uint2*)(Zr + 6);
                uint2 z3 = *(const uint2*)(Zr + 8);
                uint2 f2 = ((const uint2*)fb)[(size_t)src * 32 + u];
                float sF = blo(f2.x), vx = bhi(f2.x);
                float vy = blo(f2.y), vz = bhi(f2.y);
                float y0 = blo(z0.x), z10 = bhi(z0.x);
                float z11 = blo(z0.y), z12 = bhi(z0.y);
                float z30 = blo(z1.x), z31 = bhi(z1.x);
                float z32 = blo(z1.y), z400 = bhi(z1.y);
                float z401 = blo(z2.x), z402 = bhi(z2.x);
                float z410 = blo(z2.y), z411 = bhi(z2.y);
                float z412 = blo(z3.x), z420 = bhi(z3.x);
                float z421 = blo(z3.y), z422 = bhi(z3.y);

                g[d][0] = fmaf(y0, sF, g[d][0]);
                g[d][1] = fmaf(z30, vx, fmaf(z31, vy, fmaf(z32, vz, g[d][1])));
                g[d][2] = fmaf(z10, sF, g[d][2]);
                g[d][3] = fmaf(z11, sF, g[d][3]);
                g[d][4] = fmaf(z12, sF, g[d][4]);
                g[d][5] = fmaf(y0, vx, g[d][5]);
                g[d][6] = fmaf(y0, vy, g[d][6]);
                g[d][7] = fmaf(y0, vz, g[d][7]);
                g[d][8] = fmaf(vx, z400, fmaf(vy, z410, fmaf(vz, z420, g[d][8])));
                g[d][9] = fmaf(vx, z401, fmaf(vy, z411, fmaf(vz, z421, g[d][9])));
                g[d][10] = fmaf(vx, z402, fmaf(vy, z412, fmaf(vz, z422, g[d][10])));
            }
        }
    }
#pragma unroll
    for (int d = 0; d < 2; ++d) {
#pragma unroll
        for (int k = 0; k < 11; ++k) g[d][k] += __shfl_xor(g[d][k], 32);
        if (half == 0) {
            int row = wv * 2 + d;
            unsigned short* Gr = &Gs[row][u];
#pragma unroll
            for (int k = 0; k < 11; ++k) Gr[k * 32] = bh(g[d][k]);
        }
    }
    __syncthreads();

    int r = lane & 15, q = lane >> 4;
    bf16x8 a[11];
#pragma unroll
    for (int kk = 0; kk < 11; ++kk)
        a[kk] = *(const bf16x8*)(&Gs[r][kk * 32 + q * 8]);
    int jt = wv;  // 8 waves x 1 j-tile
    f32x4 acc = {0.f, 0.f, 0.f, 0.f};
#pragma unroll
    for (int kk = 0; kk < 11; ++kk) {
        bf16x8 b = *(const bf16x8*)(WBT + (size_t)(jt * 16 + r) * 352 + kk * 32 + q * 8);
        acc = __builtin_amdgcn_mfma_f32_16x16x32_bf16(a[kk], b, acc, 0, 0, 0);
    }
#pragma unroll
    for (int i = 0; i < 4; ++i) {
        int n = base + q * 4 + i;
        if (n < N) out[(size_t)n * 128 + jt * 16 + r] = acc[i];
    }
}

extern "C" void kernel_launch(void* const* d_in, const int* in_sizes, int n_in,
                              void* d_out, int out_size, void* d_ws, size_t ws_size,
                              hipStream_t stream) {
    const float* feat = (const float*)d_in[0];
    const float* sh = (const float*)d_in[1];
    const int* eidx = (const int*)d_in[2];
    const float* W = (const float*)d_in[3];
    float* out = (float*)d_out;
    int N = in_sizes[0] / 128;
    int E = in_sizes[1] / 9;

    float* wsf = (float*)d_ws;
    float* cg = wsf;                                       // 128 words
    int* cursor = (int*)(wsf + 128);                       // N words
    int* eorder = cursor + N;                              // E words
    unsigned* fb = (unsigned*)(eorder + E);                // 64N words
    unsigned short* WBT = (unsigned short*)(fb + (size_t)64 * N);  // 22528 words
    int* tilesums = (int*)(WBT + 45056);                   // 256 words

    int tiles = (N + 255) / 256;
    int ntiles16 = (N + 15) / 16;

    hipMemsetAsync(cursor, 0, (size_t)N * sizeof(int), stream);
    prep_kernel<<<(N * 32 + 255) / 256, 256, 0, stream>>>(feat, eidx, cursor, fb, cg, N, E);
    scanA_kernel<<<tiles, 256, 0, stream>>>(cursor, tilesums, N, W, cg, WBT);
    scanB_kernel<<<1, 256, 0, stream>>>(tilesums, tiles);
    scanC_kernel<<<tiles, 256, 0, stream>>>(cursor, tilesums, N);
    scatter_ids_kernel<<<(E + 255) / 256, 256, 0, stream>>>(eidx, cursor, eorder, E);
    gather_mfma_kernel<<<ntiles16, 512, 0, stream>>>(fb, sh, eidx, eorder, cursor, WBT, cg, out, N);
}

// Round 13
// 176.701 us; speedup vs baseline: 1.1135x; 1.1135x over previous
//
#include <hip/hip_runtime.h>
#include <math.h>

// ---------------------------------------------------------------------------
// u-space aggregation + fused MFMA epilogue (R11 structure + 64B zrec + MLP).
//   gather:  G[n][t][u] = Sum_{e->n} z_t(Y_e) (x) feat_u[src_e]  (LDS, bf16)
//   fused:   out[n][j]  = Sum_k G[n][k] * WBT[j][k]  (16x16x32 bf16 MFMA)
// Workspace (4B words):
//   cg      [0..128)        CG tensors (alpha/norm folded)
//   cursor  [128 .. +N)     memset0 -> hist -> prefix -> cursor -> row ends
//   zrec    [64B-align .. +16E)  dst-sorted 64B records (full-line writes):
//       w0=src w1=P(Y0,Z1_0) w2=P(Z1_1,Z1_2) w3=P(Z3_0,Z3_1) w4=P(Z3_2,Z4_00)
//       w5=P(Z4_01,Z4_02) w6=P(Z4_10,Z4_11) w7=P(Z4_12,Z4_20) w8=P(Z4_21,Z4_22)
//       w9..15 = 0 pad
//   fb      [.. +64N)       feat bf16 [N][32] uint2 {P(s,vx),P(vy,vz)}
//   WBT     [.. +22528)     ushort [128][352]  (W bf16, cg0/c2 folded)
//   tilesums[.. +256)       per-tile sums for hierarchical scan
// ---------------------------------------------------------------------------

typedef __attribute__((ext_vector_type(8))) short bf16x8;
typedef __attribute__((ext_vector_type(4))) float f32x4;

__device__ inline float blo(unsigned u) { return __uint_as_float(u << 16); }
__device__ inline float bhi(unsigned u) { return __uint_as_float(u & 0xffff0000u); }
__device__ inline unsigned bpack(float a, float b) {
    unsigned ua = __float_as_uint(a);
    ua = (ua + 0x7fffu + ((ua >> 16) & 1u)) >> 16;
    unsigned ub = __float_as_uint(b);
    ub = (ub + 0x7fffu + ((ub >> 16) & 1u)) & 0xffff0000u;
    return ua | ub;
}
__device__ inline unsigned short bh(float a) {
    unsigned ua = __float_as_uint(a);
    return (unsigned short)((ua + 0x7fffu + ((ua >> 16) & 1u)) >> 16);
}

// f32 factorial (all n <= 7 here; exact in f32). Register-only scalar loop.
__device__ inline float dfactf(int n) {
    float r = 1.0f;
    for (int i = 2; i <= n; ++i) r *= (float)i;
    return r;
}

// SU(2) "CG" element via the reference's exact Racah-form (all six m-dependent
// factorials in the NUMERATOR — non-standard but matches the reference).
__device__ float su2_cg_elem_f(int l1, int l2, int l3, int i, int k, int n) {
    int m1 = i - l1, m2 = k - l2, m3 = n - l3;
    if (m1 + m2 != m3) return 0.0f;
    int vmin = -l1 + l2 + m3;
    if (-l1 + m1 > vmin) vmin = -l1 + m1;
    if (0 > vmin) vmin = 0;
    int vmax = l2 + l3 + m1;
    if (l3 - l1 + l2 < vmax) vmax = l3 - l1 + l2;
    if (l3 + m3 < vmax) vmax = l3 + m3;
    if (vmax < vmin) return 0.0f;
    float c = sqrtf((float)(2 * l3 + 1) * dfactf(l3 + l1 - l2) *
                    dfactf(l3 - l1 + l2) * dfactf(l1 + l2 - l3) /
                    dfactf(l1 + l2 + l3 + 1));
    c *= sqrtf(dfactf(l3 + m3) * dfactf(l3 - m3) * dfactf(l1 - m1) *
               dfactf(l1 + m1) * dfactf(l2 - m2) * dfactf(l2 + m2));
    float s = 0.0f;
    for (int v = vmin; v <= vmax; ++v) {
        float term = dfactf(l2 + l3 + m1 - v) * dfactf(l1 - m1 + v) /
                     (dfactf(v) * dfactf(l3 - l1 + l2 - v) *
                      dfactf(l3 + m3 - v) * dfactf(v + l1 - l2 - m3));
        if ((v + l2 + m2) & 1) term = -term;
        s += term;
    }
    return c * s;
}

// cg compute by one 256-thread block. All dynamically-indexed arrays in LDS
// (runtime-indexed private arrays go to SCRATCH -> 110us straggler, rule #20).
__device__ void cg_compute_block(float* __restrict__ cg_out) {
    __shared__ float sqr[3][5][5], sqi[3][5][5];  // q matrices for l=0,1,2
    __shared__ float vals[5][45];
    int t = threadIdx.x;
    if (t < 75) {
        int l = t / 25, a = (t % 25) / 5, b = t % 5;
        float re = 0.f, im = 0.f;
        const float inv = 0.70710678118654752440f;
        int m = a - l;
        if (a < 5 && b < 5) {
            if (m < 0) {
                if (b == l - m) re = inv;        // col l+|m|
                if (b == l + m) im = -inv;       // col l-|m|
            } else if (m == 0) {
                if (b == l && a == l) re = 1.f;
            } else {
                float sgn = (m & 1) ? -1.f : 1.f;
                if (b == l + m) re = sgn * inv;
                if (b == l - m) im = sgn * inv;
            }
        }
        if (l == 1) { float r = re; re = im; im = -r; }      // * (-i)
        else if (l == 2) { re = -re; im = -im; }             // * (-1)
        sqr[l][a][b] = re;
        sqi[l][a][b] = im;
    }
    __syncthreads();
    const int l1s[5] = {0, 0, 1, 1, 1};
    const int l2s[5] = {0, 1, 0, 1, 2};
    const int l3s[5] = {0, 1, 1, 0, 1};
    const int offs[5] = {0, 1, 10, 19, 28};
    const float alphas[5] = {0.125f, 0.10206207261596575f, 0.10206207261596575f,
                             0.125f, 0.10206207261596575f};
    int p = t / 45, idx = t % 45;
    bool active = (t < 225);
    float acc = 0.0f;
    int d1 = 0, d2 = 0, d3 = 0;
    if (active) {
        int l1 = l1s[p], l2 = l2s[p], l3 = l3s[p];
        d1 = 2 * l1 + 1; d2 = 2 * l2 + 1; d3 = 2 * l3 + 1;
        if (idx < d1 * d2 * d3) {
            int j = idx / (d2 * d3);
            int rem = idx % (d2 * d3);
            int l_ = rem / d3, m = rem % d3;
            for (int i = 0; i < d1; ++i)
                for (int k = 0; k < d2; ++k)
                    for (int n = 0; n < d3; ++n) {
                        float C = su2_cg_elem_f(l1, l2, l3, i, k, n);
                        if (C == 0.0f) continue;
                        float ar = sqr[l1][i][j], ai = sqi[l1][i][j];
                        float br = sqr[l2][k][l_], bi = sqi[l2][k][l_];
                        float cr = sqr[l3][n][m], ci = sqi[l3][n][m];
                        float abr = ar * br - ai * bi;
                        float abi = ar * bi + ai * br;
                        acc += (abr * cr + abi * ci) * C;  // Re(a*b*conj(c))
                    }
        }
        vals[p][idx] = acc;
    }
    __syncthreads();
    if (active && idx < d1 * d2 * d3) {
        float n2 = 0.0f;
        for (int q = 0; q < 45; ++q) n2 += vals[p][q] * vals[p][q];
        cg_out[offs[p] + idx] = acc * alphas[p] / sqrtf(n2);
    }
}

// ---------------------------------------------------------------------------
// prep: cg (block 0, LDS-based) + feat->bf16 transcode + dst histogram
// ---------------------------------------------------------------------------
__global__ __launch_bounds__(256) void prep_kernel(
    const float* __restrict__ feat, const int* __restrict__ eidx,
    int* __restrict__ cursor, unsigned* __restrict__ fb,
    float* __restrict__ cg, int N, int E) {
    if (blockIdx.x == 0) cg_compute_block(cg);
    int t = blockIdx.x * 256 + threadIdx.x;
    if (t < N * 32) {
        int n = t >> 5, u = t & 31;
        const float* f = feat + (size_t)n * 128;
        float s = f[u];
        float vx = f[32 + 3 * u], vy = f[33 + 3 * u], vz = f[34 + 3 * u];
        ((uint2*)fb)[t] = make_uint2(bpack(s, vx), bpack(vy, vz));
    }
    if (t < E) atomicAdd(&cursor[eidx[E + t]], 1);
}

// ---------------------------------------------------------------------------
// scanA (fused with WBT build)
// WBT[j][k], k = t*32+u:  j<32 (out0): t0 -> cg0*w0, t1 -> w3
//   j>=32: w=(j-32)/3, m=(j-32)%3: t2+mm -> (mm==m)*w1 ;
//   t5+i -> c2[i][m]*w2 ; t8+mm -> (mm==m)*w4
// ---------------------------------------------------------------------------
__global__ __launch_bounds__(256) void scanA_kernel(
    const int* __restrict__ counts, int* __restrict__ tilesums, int N,
    const float* __restrict__ W, const float* __restrict__ cg,
    unsigned short* __restrict__ WBT) {
    __shared__ int lds[4];
    int i = blockIdx.x * 256 + threadIdx.x;
    int v = (i < N) ? counts[i] : 0;
#pragma unroll
    for (int d = 1; d < 64; d <<= 1) v += __shfl_xor(v, d);
    int wid = threadIdx.x >> 6;
    if ((threadIdx.x & 63) == 0) lds[wid] = v;
    __syncthreads();
    if (threadIdx.x == 0)
        tilesums[blockIdx.x] = lds[0] + lds[1] + lds[2] + lds[3];
    int idx = i;
    if (idx < 128 * 352) {
        int j = idx / 352, k = idx % 352;
        int t = k >> 5, u = k & 31;
        float val = 0.f;
        if (j < 32) {
            if (t == 0) val = cg[0] * W[u * 32 + j];
            else if (t == 1) val = W[3072 + u * 32 + j];
        } else {
            int w = (j - 32) / 3, m = (j - 32) % 3;
            if (t >= 2 && t <= 4) { if (t - 2 == m) val = W[1024 + u * 32 + w]; }
            else if (t >= 5 && t <= 7) { val = cg[10 + (t - 5) * 3 + m] * W[2048 + u * 32 + w]; }
            else if (t >= 8) { if (t - 8 == m) val = W[4096 + u * 32 + w]; }
        }
        WBT[idx] = bh(val);
    }
}

__global__ __launch_bounds__(256) void scanB_kernel(
    int* __restrict__ tilesums, int tiles) {
    __shared__ int lds[4];
    int tid = threadIdx.x;
    int v = (tid < tiles) ? tilesums[tid] : 0;
    int orig = v;
#pragma unroll
    for (int d = 1; d < 64; d <<= 1) {
        int t = __shfl_up(v, d);
        if ((tid & 63) >= d) v += t;
    }
    int wid = tid >> 6;
    if ((tid & 63) == 63) lds[wid] = v;
    __syncthreads();
    int base = 0;
    for (int q = 0; q < wid; ++q) base += lds[q];
    if (tid < tiles) tilesums[tid] = base + v - orig;  // exclusive
}

__global__ __launch_bounds__(256) void scanC_kernel(
    int* __restrict__ counts, const int* __restrict__ tilesums, int N) {
    __shared__ int lds[4];
    int i = blockIdx.x * 256 + threadIdx.x;
    int tid = threadIdx.x;
    int v = (i < N) ? counts[i] : 0;
    int orig = v;
#pragma unroll
    for (int d = 1; d < 64; d <<= 1) {
        int t = __shfl_up(v, d);
        if ((tid & 63) >= d) v += t;
    }
    int wid = tid >> 6;
    if ((tid & 63) == 63) lds[wid] = v;
    __syncthreads();
    int base = tilesums[blockIdx.x];
    for (int q = 0; q < wid; ++q) base += lds[q];
    if (i < N) counts[i] = base + v - orig;  // exclusive prefix
}

// ---------------------------------------------------------------------------
// zscatter: per edge compute 16 lane-invariant values (CG (x) Y folded),
// write one 64B-ALIGNED FULL-LINE record at the dst-sorted position
// (4x dwordx4 back-to-back -> write-combine, no RMW line fetch).
// ---------------------------------------------------------------------------
__global__ __launch_bounds__(256) void zscatter_kernel(
    const int* __restrict__ eidx, const float* __restrict__ sh,
    const float* __restrict__ cg, int* __restrict__ cursor,
    unsigned* __restrict__ zrec, int E) {
    int t = blockIdx.x * 256 + threadIdx.x;
    if (t >= E) return;
    int src = eidx[t];
    int dst = eidx[E + t];
    int pos = atomicAdd(&cursor[dst], 1);
    const float* Ye = sh + (size_t)t * 9;
    float Y0 = Ye[0];
    float Y1v[3] = {Ye[1], Ye[2], Ye[3]};
    float Y2v[5] = {Ye[4], Ye[5], Ye[6], Ye[7], Ye[8]};
    float Z1[3], Z3[3], Z4[9];
#pragma unroll
    for (int m = 0; m < 3; ++m)
        Z1[m] = fmaf(Y1v[0], cg[1 + m],
                fmaf(Y1v[1], cg[4 + m], Y1v[2] * cg[7 + m]));
#pragma unroll
    for (int i = 0; i < 3; ++i)
        Z3[i] = fmaf(Y1v[0], cg[19 + i * 3],
                fmaf(Y1v[1], cg[19 + i * 3 + 1], Y1v[2] * cg[19 + i * 3 + 2]));
#pragma unroll
    for (int i = 0; i < 3; ++i)
#pragma unroll
        for (int m = 0; m < 3; ++m) {
            float acc = 0.f;
#pragma unroll
            for (int j = 0; j < 5; ++j)
                acc = fmaf(Y2v[j], cg[28 + (i * 5 + j) * 3 + m], acc);
            Z4[i * 3 + m] = acc;
        }
    uint4* rec = (uint4*)(zrec + (size_t)pos * 16);
    rec[0] = make_uint4((unsigned)src, bpack(Y0, Z1[0]),
                        bpack(Z1[1], Z1[2]), bpack(Z3[0], Z3[1]));
    rec[1] = make_uint4(bpack(Z3[2], Z4[0]), bpack(Z4[1], Z4[2]),
                        bpack(Z4[3], Z4[4]), bpack(Z4[5], Z4[6]));
    rec[2] = make_uint4(bpack(Z4[7], Z4[8]), 0u, 0u, 0u);
    rec[3] = make_uint4(0u, 0u, 0u, 0u);
}
// After zscatter: cursor[d] == end of d's range.

// ---------------------------------------------------------------------------
// Per-edge accumulate (new 64B layout). All indices compile-time constant.
// ---------------------------------------------------------------------------
__device__ inline void edge_accum(
    uint4 q0, uint4 q1, uint2 q2, uint2 f2,
    float& g0, float& g1, float& g2, float& g3, float& g4, float& g5,
    float& g6, float& g7, float& g8, float& g9, float& g10) {
    float sF = blo(f2.x), vx = bhi(f2.x);
    float vy = blo(f2.y), vz = bhi(f2.y);
    float y0 = blo(q0.y), z10 = bhi(q0.y);
    float z11 = blo(q0.z), z12 = bhi(q0.z);
    float z30 = blo(q0.w), z31 = bhi(q0.w);
    float z32 = blo(q1.x), z400 = bhi(q1.x);
    float z401 = blo(q1.y), z402 = bhi(q1.y);
    float z410 = blo(q1.z), z411 = bhi(q1.z);
    float z412 = blo(q1.w), z420 = bhi(q1.w);
    float z421 = blo(q2.x), z422 = bhi(q2.x);
    g0 = fmaf(y0, sF, g0);                                          // t0
    g1 = fmaf(z30, vx, fmaf(z31, vy, fmaf(z32, vz, g1)));           // t1 (g3-path)
    g2 = fmaf(z10, sF, g2);  g3 = fmaf(z11, sF, g3);  g4 = fmaf(z12, sF, g4);
    g5 = fmaf(y0, vx, g5);   g6 = fmaf(y0, vy, g6);   g7 = fmaf(y0, vz, g7);
    g8 = fmaf(vx, z400, fmaf(vy, z410, fmaf(vz, z420, g8)));
    g9 = fmaf(vx, z401, fmaf(vy, z411, fmaf(vz, z421, g9)));
    g10 = fmaf(vx, z402, fmaf(vy, z412, fmaf(vz, z422, g10)));
}

// ---------------------------------------------------------------------------
// Fused gather + MFMA: one 256-thread block per 16-dst tile. Phase 1: wave wv
// gathers dsts base+wv*4..+3 (lane u=lane&31, halves alternate edges,
// 2-EDGE UNROLL for MLP, shfl_xor(32) combine) -> bf16 LDS Gs[16][360].
// Phase 2: each wave does 2 j-tiles of mfma_f32_16x16x32_bf16 vs WBT.
// D layout: lane l reg i -> out[base+(l>>4)*4+i][jt*16+(l&15)]  (verified).
// ---------------------------------------------------------------------------
__global__ __launch_bounds__(256) void gather_mfma_kernel(
    const unsigned* __restrict__ fb, const unsigned* __restrict__ zrec,
    const int* __restrict__ cursor, const unsigned short* __restrict__ WBT,
    float* __restrict__ out, int N) {
    __shared__ unsigned short Gs[16][360];
    int wv = threadIdx.x >> 6;
    int lane = threadIdx.x & 63;
    int half = lane >> 5, u = lane & 31;
    int base = blockIdx.x << 4;
    const uint2* fb2 = (const uint2*)fb;

#pragma unroll 1
    for (int d = 0; d < 4; ++d) {
        int row = wv * 4 + d;
        int node = base + row;
        if (node >= N) break;
        int start = node ? cursor[node - 1] : 0;
        int end = cursor[node];

        float g0 = 0.f, g1 = 0.f, g2 = 0.f, g3 = 0.f, g4 = 0.f, g5 = 0.f;
        float g6 = 0.f, g7 = 0.f, g8 = 0.f, g9 = 0.f, g10 = 0.f;

        int idx = start + half;
        for (; idx + 2 < end; idx += 4) {  // 2-edge unroll: idx, idx+2
            const uint4* rA = (const uint4*)(zrec + (size_t)idx * 16);
            const uint4* rB = (const uint4*)(zrec + (size_t)(idx + 2) * 16);
            uint4 a0 = rA[0], a1 = rA[1];
            uint2 a2 = *(const uint2*)(zrec + (size_t)idx * 16 + 8);
            uint4 b0 = rB[0], b1 = rB[1];
            uint2 b2 = *(const uint2*)(zrec + (size_t)(idx + 2) * 16 + 8);
            uint2 fA = fb2[(size_t)(int)a0.x * 32 + u];
            uint2 fB = fb2[(size_t)(int)b0.x * 32 + u];
            edge_accum(a0, a1, a2, fA, g0, g1, g2, g3, g4, g5, g6, g7, g8, g9, g10);
            edge_accum(b0, b1, b2, fB, g0, g1, g2, g3, g4, g5, g6, g7, g8, g9, g10);
        }
        if (idx < end) {
            const uint4* r = (const uint4*)(zrec + (size_t)idx * 16);
            uint4 q0 = r[0], q1 = r[1];
            uint2 q2 = *(const uint2*)(zrec + (size_t)idx * 16 + 8);
            uint2 f2 = fb2[(size_t)(int)q0.x * 32 + u];
            edge_accum(q0, q1, q2, f2, g0, g1, g2, g3, g4, g5, g6, g7, g8, g9, g10);
        }
        g0 += __shfl_xor(g0, 32);  g1 += __shfl_xor(g1, 32);
        g2 += __shfl_xor(g2, 32);  g3 += __shfl_xor(g3, 32);
        g4 += __shfl_xor(g4, 32);  g5 += __shfl_xor(g5, 32);
        g6 += __shfl_xor(g6, 32);  g7 += __shfl_xor(g7, 32);
        g8 += __shfl_xor(g8, 32);  g9 += __shfl_xor(g9, 32);
        g10 += __shfl_xor(g10, 32);

        if (half == 0) {
            unsigned short* Gr = &Gs[row][u];
            Gr[0] = bh(g0);        // t=0
            Gr[32] = bh(g1);       // t=1
            Gr[64] = bh(g2);  Gr[96] = bh(g3);   Gr[128] = bh(g4);
            Gr[160] = bh(g5); Gr[192] = bh(g6);  Gr[224] = bh(g7);
            Gr[256] = bh(g8); Gr[288] = bh(g9);  Gr[320] = bh(g10);
        }
    }
    __syncthreads();

    int r = lane & 15, q = lane >> 4;
    bf16x8 a[11];
#pragma unroll
    for (int kk = 0; kk < 11; ++kk)
        a[kk] = *(const bf16x8*)(&Gs[r][kk * 32 + q * 8]);

#pragma unroll
    for (int jj = 0; jj < 2; ++jj) {
        int jt = wv * 2 + jj;
        f32x4 acc = {0.f, 0.f, 0.f, 0.f};
#pragma unroll
        for (int kk = 0; kk < 11; ++kk) {
            bf16x8 b = *(const bf16x8*)(WBT + (size_t)(jt * 16 + r) * 352 + kk * 32 + q * 8);
            acc = __builtin_amdgcn_mfma_f32_16x16x32_bf16(a[kk], b, acc, 0, 0, 0);
        }
#pragma unroll
        for (int i = 0; i < 4; ++i) {
            int n = base + q * 4 + i;
            if (n < N) out[(size_t)n * 128 + jt * 16 + r] = acc[i];
        }
    }
}

extern "C" void kernel_launch(void* const* d_in, const int* in_sizes, int n_in,
                              void* d_out, int out_size, void* d_ws, size_t ws_size,
                              hipStream_t stream) {
    const float* feat = (const float*)d_in[0];
    const float* sh = (const float*)d_in[1];
    const int* eidx = (const int*)d_in[2];
    const float* W = (const float*)d_in[3];
    float* out = (float*)d_out;
    int N = in_sizes[0] / 128;
    int E = in_sizes[1] / 9;

    float* wsf = (float*)d_ws;
    float* cg = wsf;                                       // 128 words
    int* cursor = (int*)(wsf + 128);                       // N words
    size_t off = (size_t)(128 + N + 15) & ~(size_t)15;     // 64B align
    unsigned* zrec = (unsigned*)(wsf + off);               // 16E words
    unsigned* fb = zrec + (size_t)16 * E;                  // 64N words
    unsigned short* WBT = (unsigned short*)(fb + (size_t)64 * N);  // 22528 words
    int* tilesums = (int*)(WBT + 45056);                   // 256 words

    int tiles = (N + 255) / 256;
    int ntiles16 = (N + 15) / 16;

    hipMemsetAsync(cursor, 0, (size_t)N * sizeof(int), stream);
    prep_kernel<<<(N * 32 + 255) / 256, 256, 0, stream>>>(feat, eidx, cursor, fb, cg, N, E);
    scanA_kernel<<<tiles, 256, 0, stream>>>(cursor, tilesums, N, W, cg, WBT);
    scanB_kernel<<<1, 256, 0, stream>>>(tilesums, tiles);
    scanC_kernel<<<tiles, 256, 0, stream>>>(cursor, tilesums, N);
    zscatter_kernel<<<(E + 255) / 256, 256, 0, stream>>>(eidx, sh, cg, cursor, zrec, E);
    gather_mfma_kernel<<<ntiles16, 256, 0, stream>>>(fb, zrec, cursor, WBT, out, N);
}